// Round 1
// baseline (187.571 us; speedup 1.0000x reference)
//
#include <hip/hip_runtime.h>
#include <hip/hip_bf16.h>

// Problem: B=2048, D=512, all fp32.
// q = query@Wq.T+bq ; k,v likewise. attn[b,i,j]=q_i*k_j (rank-1!),
// softmax over j, out[b,i] = sum_j softmax_j(q_i*k_j)*v_j.
// => out[b,i] = f_b(q[b,i]) computed with a D-length exp reduction.

#define B_SZ 2048
#define D_SZ 512

__device__ __forceinline__ float fast_exp2(float x) {
#if defined(__has_builtin)
#if __has_builtin(__builtin_amdgcn_exp2f)
    return __builtin_amdgcn_exp2f(x);
#else
    return exp2f(x);
#endif
#else
    return exp2f(x);
#endif
}

// ---------------------------------------------------------------------------
// Kernel 1: Y = X @ W^T + bias  for (query,Wq,bq), (key,Wk,bk), (value,Wv,bv)
// selected by blockIdx.z. fp32 (no fp32 MFMA on CDNA4 -> vector ALU).
// Tile: BM=BN=64, BK=32; 256 threads; 4x4 acc per thread.
// Both X and W are row-major with k contiguous (Y = X@W.T), so both global
// loads are coalesced float4 along k. LDS stores transposed [k][m] so the
// inner loop reads contiguous float4 along m/n (b128, broadcast/2-way only).
// ---------------------------------------------------------------------------
__global__ __launch_bounds__(256) void qkv_gemm(
    const float* __restrict__ Xq, const float* __restrict__ Xk, const float* __restrict__ Xv,
    const float* __restrict__ Wq, const float* __restrict__ bq,
    const float* __restrict__ Wk, const float* __restrict__ bk,
    const float* __restrict__ Wv, const float* __restrict__ bv,
    float* __restrict__ qkv_out)
{
    const int which = blockIdx.z;
    const float* __restrict__ X    = (which == 0) ? Xq : (which == 1) ? Xk : Xv;
    const float* __restrict__ W    = (which == 0) ? Wq : (which == 1) ? Wk : Wv;
    const float* __restrict__ bias = (which == 0) ? bq : (which == 1) ? bk : bv;
    float* __restrict__ Y = qkv_out + (size_t)which * B_SZ * D_SZ;

    const int t  = threadIdx.x;
    const int tx = t & 15;        // output col group
    const int ty = t >> 4;        // output row group
    const int m0 = blockIdx.x * 64;
    const int n0 = blockIdx.y * 64;

    // +4 pad keeps float4 alignment (68*4B = 272B, mult of 16) and breaks
    // power-of-2 bank strides on the transposed staging stores.
    __shared__ float Xs[32][68];
    __shared__ float Ws[32][68];

    float acc[4][4] = {{0.f}};

    // staging indices: 64 rows x 8 float4-cols = 512 float4 per tile, 2/thread
    const int r0 = t >> 3;               // 0..31
    const int c0 = (t & 7) * 4;          // 0,4,...,28
    const int r1 = r0 + 32;              // 32..63

    for (int kk = 0; kk < D_SZ; kk += 32) {
        float4 xa0 = *(const float4*)&X[(size_t)(m0 + r0) * D_SZ + kk + c0];
        float4 xa1 = *(const float4*)&X[(size_t)(m0 + r1) * D_SZ + kk + c0];
        float4 wa0 = *(const float4*)&W[(size_t)(n0 + r0) * D_SZ + kk + c0];
        float4 wa1 = *(const float4*)&W[(size_t)(n0 + r1) * D_SZ + kk + c0];

        __syncthreads();   // previous tile fully consumed
        Xs[c0 + 0][r0] = xa0.x; Xs[c0 + 1][r0] = xa0.y;
        Xs[c0 + 2][r0] = xa0.z; Xs[c0 + 3][r0] = xa0.w;
        Xs[c0 + 0][r1] = xa1.x; Xs[c0 + 1][r1] = xa1.y;
        Xs[c0 + 2][r1] = xa1.z; Xs[c0 + 3][r1] = xa1.w;
        Ws[c0 + 0][r0] = wa0.x; Ws[c0 + 1][r0] = wa0.y;
        Ws[c0 + 2][r0] = wa0.z; Ws[c0 + 3][r0] = wa0.w;
        Ws[c0 + 0][r1] = wa1.x; Ws[c0 + 1][r1] = wa1.y;
        Ws[c0 + 2][r1] = wa1.z; Ws[c0 + 3][r1] = wa1.w;
        __syncthreads();

#pragma unroll
        for (int k = 0; k < 32; ++k) {
            float4 a = *(const float4*)&Xs[k][ty * 4];
            float4 w = *(const float4*)&Ws[k][tx * 4];
            acc[0][0] = fmaf(a.x, w.x, acc[0][0]);
            acc[0][1] = fmaf(a.x, w.y, acc[0][1]);
            acc[0][2] = fmaf(a.x, w.z, acc[0][2]);
            acc[0][3] = fmaf(a.x, w.w, acc[0][3]);
            acc[1][0] = fmaf(a.y, w.x, acc[1][0]);
            acc[1][1] = fmaf(a.y, w.y, acc[1][1]);
            acc[1][2] = fmaf(a.y, w.z, acc[1][2]);
            acc[1][3] = fmaf(a.y, w.w, acc[1][3]);
            acc[2][0] = fmaf(a.z, w.x, acc[2][0]);
            acc[2][1] = fmaf(a.z, w.y, acc[2][1]);
            acc[2][2] = fmaf(a.z, w.z, acc[2][2]);
            acc[2][3] = fmaf(a.z, w.w, acc[2][3]);
            acc[3][0] = fmaf(a.w, w.x, acc[3][0]);
            acc[3][1] = fmaf(a.w, w.y, acc[3][1]);
            acc[3][2] = fmaf(a.w, w.z, acc[3][2]);
            acc[3][3] = fmaf(a.w, w.w, acc[3][3]);
        }
    }

    const float4 bv4 = *(const float4*)&bias[n0 + tx * 4];
#pragma unroll
    for (int r = 0; r < 4; ++r) {
        float4 o;
        o.x = acc[r][0] + bv4.x;
        o.y = acc[r][1] + bv4.y;
        o.z = acc[r][2] + bv4.z;
        o.w = acc[r][3] + bv4.w;
        *(float4*)&Y[(size_t)(m0 + ty * 4 + r) * D_SZ + n0 + tx * 4] = o;
    }
}

// ---------------------------------------------------------------------------
// Kernel 2: per batch row b: out[b,i] = sum_j exp(q_i*k_j - m_i)*v_j / sum_j exp(...)
// m_i = q_i>=0 ? q_i*kmax : q_i*kmin. All in log2 domain (k pre-scaled by
// log2(e)) so the inner loop is fma -> v_exp_f32 -> add -> fma per (i,j).
// One block (256 thr) per batch element; 2 rows per thread; k,v staged as
// float2 in LDS (same-j broadcast reads -> conflict-free).
// ---------------------------------------------------------------------------
__global__ __launch_bounds__(256) void attn_kernel(
    const float* __restrict__ qkv, float* __restrict__ out)
{
    const int b = blockIdx.x;
    const int t = threadIdx.x;

    const float* __restrict__ q = qkv + (size_t)b * D_SZ;
    const float* __restrict__ k = qkv + (size_t)B_SZ * D_SZ + (size_t)b * D_SZ;
    const float* __restrict__ v = qkv + (size_t)2 * B_SZ * D_SZ + (size_t)b * D_SZ;

    __shared__ float2 kv[D_SZ];
    __shared__ float redmax[4], redmin[4];

    const float L = 1.44269504088896340736f;  // log2(e)

    float kmaxL = -3.0e38f, kminL = 3.0e38f;
#pragma unroll
    for (int j = t; j < D_SZ; j += 256) {
        float kj = k[j] * L;
        float vj = v[j];
        kv[j] = make_float2(kj, vj);
        kmaxL = fmaxf(kmaxL, kj);
        kminL = fminf(kminL, kj);
    }
    // wave (64-lane) butterfly reduce
#pragma unroll
    for (int off = 32; off > 0; off >>= 1) {
        kmaxL = fmaxf(kmaxL, __shfl_xor(kmaxL, off));
        kminL = fminf(kminL, __shfl_xor(kminL, off));
    }
    const int wave = t >> 6;
    if ((t & 63) == 0) { redmax[wave] = kmaxL; redmin[wave] = kminL; }
    __syncthreads();   // also publishes kv[]
    kmaxL = fmaxf(fmaxf(redmax[0], redmax[1]), fmaxf(redmax[2], redmax[3]));
    kminL = fminf(fminf(redmin[0], redmin[1]), fminf(redmin[2], redmin[3]));

    const int i0 = t, i1 = t + 256;
    const float q0 = q[i0];
    const float q1 = q[i1];
    const float c0 = (q0 >= 0.f) ? q0 * kmaxL : q0 * kminL;  // = L * max_j(q0*k_j)
    const float c1 = (q1 >= 0.f) ? q1 * kmaxL : q1 * kminL;

    float num0 = 0.f, den0 = 0.f, num1 = 0.f, den1 = 0.f;
#pragma unroll 8
    for (int j = 0; j < D_SZ; ++j) {
        float2 kvj = kv[j];
        float e0 = fast_exp2(fmaf(q0, kvj.x, -c0));
        float e1 = fast_exp2(fmaf(q1, kvj.x, -c1));
        den0 += e0;
        den1 += e1;
        num0 = fmaf(e0, kvj.y, num0);
        num1 = fmaf(e1, kvj.y, num1);
    }
    out[(size_t)b * D_SZ + i0] = num0 / den0;
    out[(size_t)b * D_SZ + i1] = num1 / den1;
}

extern "C" void kernel_launch(void* const* d_in, const int* in_sizes, int n_in,
                              void* d_out, int out_size, void* d_ws, size_t ws_size,
                              hipStream_t stream) {
    const float* query = (const float*)d_in[0];
    const float* key_  = (const float*)d_in[1];
    const float* value = (const float*)d_in[2];
    const float* Wq    = (const float*)d_in[3];
    const float* bq    = (const float*)d_in[4];
    const float* Wk    = (const float*)d_in[5];
    const float* bk    = (const float*)d_in[6];
    const float* Wv    = (const float*)d_in[7];
    const float* bv    = (const float*)d_in[8];
    float* out = (float*)d_out;

    float* qkv = (float*)d_ws;  // [3][B][D] fp32 = 12.6 MB

    dim3 g1(B_SZ / 64, D_SZ / 64, 3);
    qkv_gemm<<<g1, 256, 0, stream>>>(query, key_, value, Wq, bq, Wk, bk, Wv, bv, qkv);
    attn_kernel<<<B_SZ, 256, 0, stream>>>(qkv, out);
}